// Round 7
// baseline (1237.924 us; speedup 1.0000x reference)
//
#include <hip/hip_runtime.h>
#include <hip/hip_bf16.h>
#include <hip/hip_cooperative_groups.h>

namespace cgx = cooperative_groups;

#define H 1024
#define PH 512
#define MROWS 16384
#define DT 0.1f
#define LN_EPS 1e-5f

#define BM 128
#define BN 128
#define BK 64

typedef short s16x8 __attribute__((ext_vector_type(8)));
typedef float f32x4 __attribute__((ext_vector_type(4)));

__device__ __forceinline__ float b2f(short v) {
    union { float f; unsigned u; } c;
    c.u = ((unsigned)(unsigned short)v) << 16;
    return c.f;
}
__device__ __forceinline__ short f2b(float f) {
    union { float f; unsigned u; } c;
    c.f = f;
    unsigned u = c.u;
    unsigned r = u + 0x7FFFu + ((u >> 16) & 1u);  // RNE
    return (short)(r >> 16);
}
// fast tanh: t = 1 - 2/(e^{2s}+1); exact at +/-inf, ~1e-6 abs err (output is bf16)
__device__ __forceinline__ float ftanh(float s) {
    float e = __expf(2.0f * s);
    return 1.0f - 2.0f * __builtin_amdgcn_rcpf(e + 1.0f);
}

// ---------------- device stage pieces (shared by mega kernel + fallbacks) ----

// prep, one 64x64 tile (b in 0..255). LDS use: 64*65*4 + 64*66*2 = 25088 B.
//   Wsym[i][j]   = bf16(S[i,j]-S[j,i]);  WsymT = -Wsym (== Wsym^T)
//   W1b          = bf16(W1)
//   WflowT[k][i] = sign(i>=512) * bf16(W1[k][(i+512)&1023])
//   Wfd[i][k]    = bf16( DT * WflowT[k][i] )
__device__ __forceinline__ void prep_tile(char* smem,
        const float* S, const float* W1,
        short* Wsym, short* WsymT, short* W1b, short* WflowT, short* Wfd,
        int b, int tid) {
    float (*T1)[65] = (float (*)[65])smem;                 // 16640 B
    short (*Ts)[66] = (short (*)[66])(smem + 64 * 65 * 4); //  8448 B
    const int I = (b >> 4) * 64, J = (b & 15) * 64;
    const int c = tid & 63, r0 = (tid >> 6) * 16;
#pragma unroll
    for (int rr = 0; rr < 16; ++rr) {
        int r = r0 + rr;
        T1[r][c] = S[(size_t)(J + r) * H + I + c];
    }
    __syncthreads();
    const int pJ = (J + PH) & (H - 1);
    const short sflip = (J >= PH) ? (short)0x8000 : (short)0;
#pragma unroll
    for (int rr = 0; rr < 16; ++rr) {
        int r = r0 + rr;
        size_t rowb = (size_t)(I + r) * H;
        float d = S[rowb + J + c] - T1[c][r];   // S[i][j] - S[j][i]
        Wsym [rowb + J + c] = f2b(d);
        WsymT[rowb + J + c] = f2b(-d);
        W1b  [rowb + J + c] = f2b(W1[rowb + J + c]);
        short wt = (short)(f2b(W1[rowb + pJ + c]) ^ sflip);
        WflowT[rowb + J + c] = wt;
        Ts[r][c] = wt;
    }
    __syncthreads();
#pragma unroll
    for (int rr = 0; rr < 16; ++rr) {
        int r = r0 + rr;                       // i = J + r, k = I + c
        Wfd[(size_t)(J + r) * H + I + c] = f2b(DT * b2f(Ts[c][r]));
    }
}

// x (fp32) -> xb (bf16), grid-stride piece for blocks 256..1023 of the mega grid
__device__ __forceinline__ void cvt_piece(const float* x, short* xb, int b, int tid) {
    const int N8 = MROWS * H / 8;              // 2097152
    for (int t = (b - 256) * 256 + tid; t < N8; t += 768 * 256) {
        const float4* p = (const float4*)x + (size_t)t * 2;
        float4 f0 = p[0], f1 = p[1];
        s16x8 v;
        v[0] = f2b(f0.x); v[1] = f2b(f0.y); v[2] = f2b(f0.z); v[3] = f2b(f0.w);
        v[4] = f2b(f1.x); v[5] = f2b(f1.y); v[6] = f2b(f1.z); v[7] = f2b(f1.w);
        ((s16x8*)xb)[t] = v;
    }
}

// C[m,n] = sum_k A[m,k] * Bw[n,k]  (B^T GEMM), bf16 MFMA.
// Proven core: single-buffered LDS (32KB), global_load_lds width=16,
// both-sides XOR swizzle (conflict-free), swapped-operand MFMA
// (lane: row=lane&15, 4 consecutive cols).
// KIND 0: out = bf16( xf[m,n] + acc )               (Wu prep; fallback z0)
// KIND 1: t = ftanh(acc + xf[n]); out = bf16((1-t^2)*w2f[n])    (fallback g)
// KIND 2: out = bf16( out + clamp(acc, +/-clampv) )  (fallback RMW; B pre-scaled)
// KIND 3: out = bf16(acc) [u0]; out2 = bf16((1-tanh(acc+xf)^2)*w2f) [gate0]
// KIND 4: us = u0r + acc; gate = (1-tanh(us+xf)^2)*w2f; out2 = bf16(pg + gate)
// KIND 5: out = bf16( DT * acc )                     (GT precompute)
// KIND 7: K=2048 fused: A=[A|A2], B=[Bw|B2]; out = bf16(acc)    (y-delta)
template <int KIND>
__device__ __forceinline__ void gemm_core(char* smem,
        const short* A, const short* Bw, short* out,
        const float* xf, const float* w2f,
        const short* u0r, const short* pg, short* out2,
        const short* A2, const short* B2,
        int m0, int n0, int tid, float clampv) {
    short* As = (short*)smem;            // 16KB
    short* Bs = (short*)(smem + 16384);  // 16KB

    const int lane = tid & 63;
    const int wave = tid >> 6;
    const int wm   = wave >> 1;      // 0..1
    const int wn   = wave & 1;       // 0..1
    const int lrow = lane & 15;
    const int quad = lane >> 4;
    const int swzr = (lrow & 7) << 4;                  // read-side XOR (bytes)
    const int srow  = lane >> 3;                       // 0..7 == row&7
    const int selem = 8 * ((lane & 7) ^ srow);         // pre-swizzled src column

    f32x4 acc[4][4] = {};

    const int KSTEPS = (KIND == 7) ? (2 * H / BK) : (H / BK);
    for (int t = 0; t < KSTEPS; ++t) {
        const int k0 = t * BK;
        const short* Au = A;
        const short* Bu = Bw;
        if (KIND == 7 && k0 >= H) { Au = A2; Bu = B2; }
        const int kk = k0 & (H - 1);
#pragma unroll
        for (int i = 0; i < 4; ++i) {
            int ch = wave * 4 + i;                     // 16 chunks of 8 rows
            const short* asrc = Au + (size_t)(m0 + ch * 8 + srow) * H + kk + selem;
            const short* bsrc = Bu + (size_t)(n0 + ch * 8 + srow) * H + kk + selem;
            __builtin_amdgcn_global_load_lds(
                (const __attribute__((address_space(1))) void*)asrc,
                (__attribute__((address_space(3))) void*)(As + ch * 512), 16, 0, 0);
            __builtin_amdgcn_global_load_lds(
                (const __attribute__((address_space(1))) void*)bsrc,
                (__attribute__((address_space(3))) void*)(Bs + ch * 512), 16, 0, 0);
        }
        __syncthreads();

#pragma unroll
        for (int ks = 0; ks < 2; ++ks) {
            s16x8 af[4], bfr[4];
#pragma unroll
            for (int mt = 0; mt < 4; ++mt) {
                int row = wm * 64 + mt * 16 + lrow;
                af[mt] = *(const s16x8*)((const char*)As + row * 128 +
                                         ((ks * 64 + quad * 16) ^ swzr));
            }
#pragma unroll
            for (int nt = 0; nt < 4; ++nt) {
                int col = wn * 64 + nt * 16 + lrow;
                bfr[nt] = *(const s16x8*)((const char*)Bs + col * 128 +
                                          ((ks * 64 + quad * 16) ^ swzr));
            }
#pragma unroll
            for (int mt = 0; mt < 4; ++mt)
#pragma unroll
                for (int nt = 0; nt < 4; ++nt)
                    acc[mt][nt] = __builtin_amdgcn_mfma_f32_16x16x32_bf16(
                        bfr[nt], af[mt], acc[mt][nt], 0, 0, 0);  // swapped: D[row][col]
        }
        __syncthreads();
    }

    // epilogue (swapped layout): row = lane&15, cols = quad*4 + 0..3
    float4 bvv[4], wvv[4];
    if (KIND == 1 || KIND == 3 || KIND == 4) {
#pragma unroll
        for (int nt = 0; nt < 4; ++nt) {
            int col = n0 + wn * 64 + nt * 16 + quad * 4;
            bvv[nt] = *(const float4*)(xf + col);
            wvv[nt] = *(const float4*)(w2f + col);
        }
    }
#pragma unroll
    for (int mt = 0; mt < 4; ++mt) {
        const int row = m0 + wm * 64 + mt * 16 + lrow;
        const size_t rbase = (size_t)row * H;
#pragma unroll
        for (int nt = 0; nt < 4; ++nt) {
            const int col = n0 + wn * 64 + nt * 16 + quad * 4;
            const size_t idx = rbase + col;
            f32x4 a = acc[mt][nt];
            short4 o;
            if (KIND == 0) {
                float4 xv = *(const float4*)(xf + idx);
                o.x = f2b(a[0] + xv.x);
                o.y = f2b(a[1] + xv.y);
                o.z = f2b(a[2] + xv.z);
                o.w = f2b(a[3] + xv.w);
                *(short4*)(out + idx) = o;
            } else if (KIND == 1) {
                float t0 = ftanh(a[0] + bvv[nt].x);
                float t1 = ftanh(a[1] + bvv[nt].y);
                float t2 = ftanh(a[2] + bvv[nt].z);
                float t3 = ftanh(a[3] + bvv[nt].w);
                o.x = f2b((1.0f - t0 * t0) * wvv[nt].x);
                o.y = f2b((1.0f - t1 * t1) * wvv[nt].y);
                o.z = f2b((1.0f - t2 * t2) * wvv[nt].z);
                o.w = f2b((1.0f - t3 * t3) * wvv[nt].w);
                *(short4*)(out + idx) = o;
            } else if (KIND == 2) {
                short4 zo = *(const short4*)(out + idx);
                float d0 = fminf(fmaxf(a[0], -clampv), clampv);
                float d1 = fminf(fmaxf(a[1], -clampv), clampv);
                float d2 = fminf(fmaxf(a[2], -clampv), clampv);
                float d3 = fminf(fmaxf(a[3], -clampv), clampv);
                o.x = f2b(b2f(zo.x) + d0);
                o.y = f2b(b2f(zo.y) + d1);
                o.z = f2b(b2f(zo.z) + d2);
                o.w = f2b(b2f(zo.w) + d3);
                *(short4*)(out + idx) = o;
            } else if (KIND == 3) {
                short4 u;                       // u0 = bf16(acc)
                u.x = f2b(a[0]); u.y = f2b(a[1]); u.z = f2b(a[2]); u.w = f2b(a[3]);
                *(short4*)(out + idx) = u;
                float t0 = ftanh(a[0] + bvv[nt].x);
                float t1 = ftanh(a[1] + bvv[nt].y);
                float t2 = ftanh(a[2] + bvv[nt].z);
                float t3 = ftanh(a[3] + bvv[nt].w);
                o.x = f2b((1.0f - t0 * t0) * wvv[nt].x);
                o.y = f2b((1.0f - t1 * t1) * wvv[nt].y);
                o.z = f2b((1.0f - t2 * t2) * wvv[nt].z);
                o.w = f2b((1.0f - t3 * t3) * wvv[nt].w);
                *(short4*)(out2 + idx) = o;     // gsum0 = gate0
            } else if (KIND == 4) {
                short4 u4 = *(const short4*)(u0r + idx);
                short4 p4 = *(const short4*)(pg + idx);
                float t0 = ftanh(b2f(u4.x) + a[0] + bvv[nt].x);
                float t1 = ftanh(b2f(u4.y) + a[1] + bvv[nt].y);
                float t2 = ftanh(b2f(u4.z) + a[2] + bvv[nt].z);
                float t3 = ftanh(b2f(u4.w) + a[3] + bvv[nt].w);
                o.x = f2b(b2f(p4.x) + (1.0f - t0 * t0) * wvv[nt].x);
                o.y = f2b(b2f(p4.y) + (1.0f - t1 * t1) * wvv[nt].y);
                o.z = f2b(b2f(p4.z) + (1.0f - t2 * t2) * wvv[nt].z);
                o.w = f2b(b2f(p4.w) + (1.0f - t3 * t3) * wvv[nt].w);
                *(short4*)(out2 + idx) = o;     // gsum_s = gsum_{s-1} + gate_s
            } else if (KIND == 5) {              // GT = bf16(DT*acc)
                o.x = f2b(DT * a[0]);
                o.y = f2b(DT * a[1]);
                o.z = f2b(DT * a[2]);
                o.w = f2b(DT * a[3]);
                *(short4*)(out + idx) = o;
            } else {                             // KIND 7: z-delta = bf16(acc)
                o.x = f2b(a[0]);
                o.y = f2b(a[1]);
                o.z = f2b(a[2]);
                o.w = f2b(a[3]);
                *(short4*)(out + idx) = o;
            }
        }
    }
}

// One LayerNorm row: y = xmul*x + z; out fp32. smem needs 32 B (ss/qs).
__device__ __forceinline__ void ln_row(char* smem,
        const short* z, const float* x, const float* gamma, const float* beta,
        float* out, int row, int tid, float xmul) {
    float* ss = (float*)smem;
    float* qs = ss + 4;
    const size_t base = (size_t)row * H;
    short4 z4 = ((const short4*)(z + base))[tid];
    float4 x4 = ((const float4*)(x + base))[tid];
    float y0 = fmaf(xmul, x4.x, b2f(z4.x));
    float y1 = fmaf(xmul, x4.y, b2f(z4.y));
    float y2 = fmaf(xmul, x4.z, b2f(z4.z));
    float y3 = fmaf(xmul, x4.w, b2f(z4.w));
    float s = y0 + y1 + y2 + y3;
    float q = y0 * y0 + y1 * y1 + y2 * y2 + y3 * y3;
#pragma unroll
    for (int off = 32; off > 0; off >>= 1) {
        s += __shfl_down(s, off);
        q += __shfl_down(q, off);
    }
    __syncthreads();                              // ss/qs reuse across rows
    if ((tid & 63) == 0) { ss[tid >> 6] = s; qs[tid >> 6] = q; }
    __syncthreads();
    s = ss[0] + ss[1] + ss[2] + ss[3];
    q = qs[0] + qs[1] + qs[2] + qs[3];
    const float mu  = s * (1.0f / H);
    const float var = q * (1.0f / H) - mu * mu;
    const float rs  = rsqrtf(var + LN_EPS);
    const int col = tid * 4;
    float4 o;
    o.x = (y0 - mu) * rs * gamma[col + 0] + beta[col + 0];
    o.y = (y1 - mu) * rs * gamma[col + 1] + beta[col + 1];
    o.z = (y2 - mu) * rs * gamma[col + 2] + beta[col + 2];
    o.w = (y3 - mu) * rs * gamma[col + 3] + beta[col + 3];
    ((float4*)(out + base))[tid] = o;
}

// ---------------- mega kernel: whole fast-path pipeline, 1 dispatch ----------
// grid 1024 x 256, LDS 32KB, VGPR<=128 (launch_bounds(256,4)) => 4 blocks/CU,
// exactly 1024 co-resident blocks; validated by cooperative launch.
__global__ __launch_bounds__(256, 4)
void mega_k(const float* S, const float* W1, const float* x,
            const float* b1, const float* w2,
            const float* gamma, const float* beta,
            short* Wsym, short* WsymT, short* W1b, short* WflowT, short* Wfd,
            short* Wu, short* GT, short* xb, short* u0,
            short* gsumA, short* gsumB, float* out) {
    __shared__ __align__(16) char smem[32768];
    const int b = blockIdx.x, tid = threadIdx.x;
    cgx::grid_group grid = cgx::this_grid();

    // stage P: prep (blocks 0..255) || cvt x->bf16 (blocks 256..1023)
    if (b < 256) prep_tile(smem, S, W1, Wsym, WsymT, W1b, WflowT, Wfd, b, tid);
    else         cvt_piece(x, xb, b, tid);
    grid.sync();

    // stage S: Wu = W1 + W1b@WsymT^T  ||  GT = DT*(W1b@WflowT^T)   (concurrent)
    if (b < 64) {
        gemm_core<0>(smem, W1b, WsymT, Wu, W1, nullptr, nullptr, nullptr, nullptr,
                     nullptr, nullptr, (b >> 3) * BM, (b & 7) * BN, tid, 0.0f);
    } else if (b < 128) {
        int bb = b - 64;
        gemm_core<5>(smem, W1b, WflowT, GT, nullptr, nullptr, nullptr, nullptr,
                     nullptr, nullptr, nullptr, (bb >> 3) * BM, (bb & 7) * BN, tid, 0.0f);
    }
    grid.sync();

    // big-GEMM block decode: bijective XCD swizzle
    const int chunk = ((b & 7) << 7) | (b >> 3);
    const int m0 = (chunk >> 3) * BM;
    const int n0 = (chunk & 7) * BN;

    // u0 = x@Wu^T ; gsumA = gate0
    gemm_core<3>(smem, xb, Wu, u0, b1, w2, nullptr, nullptr, gsumA,
                 nullptr, nullptr, m0, n0, tid, 0.0f);
    grid.sync();
    // gsumB = gsumA + gate1
    gemm_core<4>(smem, gsumA, GT, nullptr, b1, w2, u0, gsumA, gsumB,
                 nullptr, nullptr, m0, n0, tid, 0.0f);
    grid.sync();
    // gsumA = gsumB + gate2
    gemm_core<4>(smem, gsumB, GT, nullptr, b1, w2, u0, gsumB, gsumA,
                 nullptr, nullptr, m0, n0, tid, 0.0f);
    grid.sync();
    // z = x@Wsym^T + gsumA@Wfd^T  (K=2048 fused) -> gsumB (dead)
    gemm_core<7>(smem, xb, Wsym, gsumB, nullptr, nullptr, nullptr, nullptr, nullptr,
                 gsumA, Wfd, m0, n0, tid, 0.0f);
    grid.sync();
    // LayerNorm: y = 2x + z; 16 rows per block
    for (int r = 0; r < 16; ++r)
        ln_row(smem, gsumB, x, gamma, beta, out, b * 16 + r, tid, 2.0f);
}

// ---------------- fallback standalone kernels ----------------
__global__ __launch_bounds__(256)
void prep_k(const float* __restrict__ S, const float* __restrict__ W1,
            short* __restrict__ Wsym, short* __restrict__ WsymT,
            short* __restrict__ W1b, short* __restrict__ WflowT,
            short* __restrict__ Wfd) {
    __shared__ __align__(16) char smem[32768];
    prep_tile(smem, S, W1, Wsym, WsymT, W1b, WflowT, Wfd, blockIdx.x, threadIdx.x);
}

__global__ __launch_bounds__(256)
void cvt_x(const float* __restrict__ x, short* __restrict__ xb) {
    int t = blockIdx.x * 256 + threadIdx.x;
    const float4* p = (const float4*)x + (size_t)t * 2;
    float4 f0 = p[0], f1 = p[1];
    s16x8 v;
    v[0] = f2b(f0.x); v[1] = f2b(f0.y); v[2] = f2b(f0.z); v[3] = f2b(f0.w);
    v[4] = f2b(f1.x); v[5] = f2b(f1.y); v[6] = f2b(f1.z); v[7] = f2b(f1.w);
    ((s16x8*)xb)[t] = v;
}

template <int KIND, bool G2D>
__global__ __launch_bounds__(256, 4)
void gemm_k(const short* A, const short* Bw, short* out,
            const float* xf, const float* w2f,
            const short* u0r, const short* pg, short* out2,
            const short* A2, const short* B2, float clampv) {
    __shared__ __align__(16) char smem[32768];
    int m0, n0;
    if (G2D) {
        m0 = blockIdx.y * BM;
        n0 = blockIdx.x * BN;
    } else {
        const int lid   = blockIdx.x;
        const int chunk = ((lid & 7) << 7) | (lid >> 3);
        m0 = (chunk >> 3) * BM;
        n0 = (chunk & 7) * BN;
    }
    gemm_core<KIND>(smem, A, Bw, out, xf, w2f, u0r, pg, out2, A2, B2,
                    m0, n0, threadIdx.x, clampv);
}

__global__ __launch_bounds__(256)
void ln_k(const short* __restrict__ z, const float* __restrict__ x,
          const float* __restrict__ gamma, const float* __restrict__ beta,
          float* __restrict__ out, float xmul) {
    __shared__ __align__(16) char smem[64];
    ln_row(smem, z, x, gamma, beta, out, blockIdx.x, threadIdx.x, xmul);
}

extern "C" void kernel_launch(void* const* d_in, const int* in_sizes, int n_in,
                              void* d_out, int out_size, void* d_ws, size_t ws_size,
                              hipStream_t stream) {
    int ix = 0;
    for (int i = 0; i < n_in; ++i)
        if (in_sizes[i] == MROWS * H) { ix = i; break; }

    const float *x, *S, *W1, *b1, *w2, *gamma, *beta;
    if (ix == 0) {
        // dict order: x,S,W1,b1,w2,b2,J,gamma,beta,num_steps
        x     = (const float*)d_in[0];
        S     = (const float*)d_in[1];
        W1    = (const float*)d_in[2];
        b1    = (const float*)d_in[3];
        w2    = (const float*)d_in[4];
        gamma = (const float*)d_in[7];
        beta  = (const float*)d_in[8];
    } else {
        // sorted-key order: J,S,W1,b1,b2,beta,gamma,num_steps,w2,x
        S     = (const float*)d_in[1];
        W1    = (const float*)d_in[2];
        b1    = (const float*)d_in[3];
        beta  = (const float*)d_in[5];
        gamma = (const float*)d_in[6];
        w2    = (const float*)d_in[8];
        x     = (const float*)d_in[ix];
    }

    const size_t MB = 1024 * 1024;
    // d_out (64MB):
    //   [0..32):  u0 (bf16, written by KIND3, dead after last KIND4)
    //   [32..46): Wsym | WsymT | W1b | WflowT | Wfd | Wu | GT   (2MB each)
    //   final LN overwrites all 64MB with fp32 out.
    float* out    = (float*)d_out;
    short* u0     = (short*)d_out;
    char*  hi     = (char*)d_out + 32 * MB;
    short* Wsym   = (short*)(hi);
    short* WsymT  = (short*)(hi + 2 * MB);
    short* W1b    = (short*)(hi + 4 * MB);
    short* WflowT = (short*)(hi + 6 * MB);
    short* Wfd    = (short*)(hi + 8 * MB);
    short* Wu     = (short*)(hi + 10 * MB);
    short* GT     = (short*)(hi + 12 * MB);
    // d_ws (fast, >=96MB): [0..32) xb | [32..64) gsumA | [64..96) gsumB -> z
    short* xb     = (short*)d_ws;
    short* gsumA  = (short*)((char*)d_ws + 32 * MB);
    short* gsumB  = (short*)((char*)d_ws + 64 * MB);
    short* z      = gsumB;

    const bool fast = ws_size >= 96 * MB;
    const int  nblk = (H / BN) * (MROWS / BM);  // 1024

    if (fast) {
        void* args[] = {
            (void*)&S, (void*)&W1, (void*)&x, (void*)&b1, (void*)&w2,
            (void*)&gamma, (void*)&beta,
            (void*)&Wsym, (void*)&WsymT, (void*)&W1b, (void*)&WflowT, (void*)&Wfd,
            (void*)&Wu, (void*)&GT, (void*)&xb, (void*)&u0,
            (void*)&gsumA, (void*)&gsumB, (void*)&out
        };
        hipError_t e = hipLaunchCooperativeKernel(
            reinterpret_cast<void*>(mega_k), dim3(1024), dim3(256), args, 0, stream);
        if (e == hipSuccess) return;
        (void)hipGetLastError();  // clear; fall through to multi-dispatch path
    }

    prep_k<<<256, 256, 0, stream>>>(S, W1, Wsym, WsymT, W1b, WflowT, Wfd);

    if (fast) {
        cvt_x<<<(MROWS * H / 8) / 256, 256, 0, stream>>>(x, xb);
        gemm_k<0, true><<<dim3(H / BN, H / BM), 256, 0, stream>>>(
            W1b, WsymT, Wu, W1, nullptr, nullptr, nullptr, nullptr,
            nullptr, nullptr, 0.0f);
        gemm_k<5, true><<<dim3(H / BN, H / BM), 256, 0, stream>>>(
            W1b, WflowT, GT, nullptr, nullptr, nullptr, nullptr, nullptr,
            nullptr, nullptr, 0.0f);
        gemm_k<3, false><<<nblk, 256, 0, stream>>>(
            xb, Wu, u0, b1, w2, nullptr, nullptr, gsumA,
            nullptr, nullptr, 0.0f);
        gemm_k<4, false><<<nblk, 256, 0, stream>>>(
            gsumA, GT, nullptr, b1, w2, u0, gsumA, gsumB,
            nullptr, nullptr, 0.0f);
        gemm_k<4, false><<<nblk, 256, 0, stream>>>(
            gsumB, GT, nullptr, b1, w2, u0, gsumB, gsumA,
            nullptr, nullptr, 0.0f);
        gemm_k<7, false><<<nblk, 256, 0, stream>>>(
            xb, Wsym, z, nullptr, nullptr, nullptr, nullptr, nullptr,
            gsumA, Wfd, 0.0f);
        ln_k<<<MROWS, 256, 0, stream>>>(z, x, gamma, beta, out, 2.0f);
    } else {
        // fallback (ws >= 32MB): proven 7-GEMM sequence; y = x + z
        short* xbo = (short*)d_out;          // xb in d_out, dead after KIND0
        short* go  = (short*)d_out;          // then reused as g
        short* zf  = (short*)d_ws;
        cvt_x<<<(MROWS * H / 8) / 256, 256, 0, stream>>>(x, xbo);
        gemm_k<0, false><<<nblk, 256, 0, stream>>>(
            xbo, Wsym, zf, x, nullptr, nullptr, nullptr, nullptr,
            nullptr, nullptr, 0.0f);
        for (int step = 0; step < 3; ++step) {
            gemm_k<1, false><<<nblk, 256, 0, stream>>>(
                zf, W1b, go, b1, w2, nullptr, nullptr, nullptr,
                nullptr, nullptr, 0.0f);
            gemm_k<2, false><<<nblk, 256, 0, stream>>>(
                go, Wfd, zf, nullptr, nullptr, nullptr, nullptr, nullptr,
                nullptr, nullptr, 0.01f);
        }
        ln_k<<<MROWS, 256, 0, stream>>>(zf, x, gamma, beta, out, 1.0f);
    }
}

// Round 8
// 406.755 us; speedup vs baseline: 3.0434x; 3.0434x over previous
//
#include <hip/hip_runtime.h>
#include <hip/hip_bf16.h>

#define H 1024
#define PH 512
#define MROWS 16384
#define DT 0.1f
#define LN_EPS 1e-5f

#define BM 128
#define BN 128
#define BK 64

typedef short s16x8 __attribute__((ext_vector_type(8)));
typedef float f32x4 __attribute__((ext_vector_type(4)));

__device__ __forceinline__ float b2f(short v) {
    union { float f; unsigned u; } c;
    c.u = ((unsigned)(unsigned short)v) << 16;
    return c.f;
}
__device__ __forceinline__ short f2b(float f) {
    union { float f; unsigned u; } c;
    c.f = f;
    unsigned u = c.u;
    unsigned r = u + 0x7FFFu + ((u >> 16) & 1u);  // RNE
    return (short)(r >> 16);
}
// fast tanh: t = 1 - 2/(e^{2s}+1); exact at +/-inf, ~1e-6 abs err (output is bf16)
__device__ __forceinline__ float ftanh(float s) {
    float e = __expf(2.0f * s);
    return 1.0f - 2.0f * __builtin_amdgcn_rcpf(e + 1.0f);
}

// ---------------- device stage pieces ----------------

// prep, one 64x64 tile (b in 0..255). LDS use: 64*65*4 + 64*66*2 = 25088 B.
//   Wsym[i][j]   = bf16(S[i,j]-S[j,i]);  WsymT = -Wsym (== Wsym^T)
//   W1b          = bf16(W1)
//   WflowT[k][i] = sign(i>=512) * bf16(W1[k][(i+512)&1023])
//   Wfd[i][k]    = bf16( DT * WflowT[k][i] )
__device__ __forceinline__ void prep_tile(char* smem,
        const float* S, const float* W1,
        short* Wsym, short* WsymT, short* W1b, short* WflowT, short* Wfd,
        int b, int tid) {
    float (*T1)[65] = (float (*)[65])smem;                 // 16640 B
    short (*Ts)[66] = (short (*)[66])(smem + 64 * 65 * 4); //  8448 B
    const int I = (b >> 4) * 64, J = (b & 15) * 64;
    const int c = tid & 63, r0 = (tid >> 6) * 16;
#pragma unroll
    for (int rr = 0; rr < 16; ++rr) {
        int r = r0 + rr;
        T1[r][c] = S[(size_t)(J + r) * H + I + c];
    }
    __syncthreads();
    const int pJ = (J + PH) & (H - 1);
    const short sflip = (J >= PH) ? (short)0x8000 : (short)0;
#pragma unroll
    for (int rr = 0; rr < 16; ++rr) {
        int r = r0 + rr;
        size_t rowb = (size_t)(I + r) * H;
        float d = S[rowb + J + c] - T1[c][r];   // S[i][j] - S[j][i]
        Wsym [rowb + J + c] = f2b(d);
        WsymT[rowb + J + c] = f2b(-d);
        W1b  [rowb + J + c] = f2b(W1[rowb + J + c]);
        short wt = (short)(f2b(W1[rowb + pJ + c]) ^ sflip);
        WflowT[rowb + J + c] = wt;
        Ts[r][c] = wt;
    }
    __syncthreads();
#pragma unroll
    for (int rr = 0; rr < 16; ++rr) {
        int r = r0 + rr;                       // i = J + r, k = I + c
        Wfd[(size_t)(J + r) * H + I + c] = f2b(DT * b2f(Ts[c][r]));
    }
}

// C[m,n] = sum_k A[m,k] * Bw[n,k]  (B^T GEMM), bf16 MFMA.
// Proven core: single-buffered LDS (32KB), global_load_lds width=16,
// both-sides XOR swizzle (conflict-free), swapped-operand MFMA
// (lane: row=lane&15, 4 consecutive cols).
// KIND 0: out = bf16( xf[m,n] + acc )               (Wu prep; fallback z0)
// KIND 1: t = ftanh(acc + xf[n]); out = bf16((1-t^2)*w2f[n])    (fallback g)
// KIND 2: out = bf16( out + clamp(acc, +/-clampv) )  (fallback RMW; B pre-scaled)
// KIND 3: out = bf16(acc) [u0]; out2 = bf16((1-tanh(acc+xf)^2)*w2f) [gate0]
// KIND 4: us = u0r + acc; gate = (1-tanh(us+xf)^2)*w2f; out2 = bf16(pg + gate)
// KIND 5: out = bf16( DT * acc )                     (GT precompute)
// KIND 7: K=2048 fused: A=[A|A2], B=[Bw|B2]; out = bf16(acc)    (y-delta)
template <int KIND>
__device__ __forceinline__ void gemm_core(char* smem,
        const short* A, const short* Bw, short* out,
        const float* xf, const float* w2f,
        const short* u0r, const short* pg, short* out2,
        const short* A2, const short* B2,
        int m0, int n0, int tid, float clampv) {
    short* As = (short*)smem;            // 16KB
    short* Bs = (short*)(smem + 16384);  // 16KB

    const int lane = tid & 63;
    const int wave = tid >> 6;
    const int wm   = wave >> 1;      // 0..1
    const int wn   = wave & 1;       // 0..1
    const int lrow = lane & 15;
    const int quad = lane >> 4;
    const int swzr = (lrow & 7) << 4;                  // read-side XOR (bytes)
    const int srow  = lane >> 3;                       // 0..7 == row&7
    const int selem = 8 * ((lane & 7) ^ srow);         // pre-swizzled src column

    f32x4 acc[4][4] = {};

    const int KSTEPS = (KIND == 7) ? (2 * H / BK) : (H / BK);
    for (int t = 0; t < KSTEPS; ++t) {
        const int k0 = t * BK;
        const short* Au = A;
        const short* Bu = Bw;
        if (KIND == 7 && k0 >= H) { Au = A2; Bu = B2; }
        const int kk = k0 & (H - 1);
#pragma unroll
        for (int i = 0; i < 4; ++i) {
            int ch = wave * 4 + i;                     // 16 chunks of 8 rows
            const short* asrc = Au + (size_t)(m0 + ch * 8 + srow) * H + kk + selem;
            const short* bsrc = Bu + (size_t)(n0 + ch * 8 + srow) * H + kk + selem;
            __builtin_amdgcn_global_load_lds(
                (const __attribute__((address_space(1))) void*)asrc,
                (__attribute__((address_space(3))) void*)(As + ch * 512), 16, 0, 0);
            __builtin_amdgcn_global_load_lds(
                (const __attribute__((address_space(1))) void*)bsrc,
                (__attribute__((address_space(3))) void*)(Bs + ch * 512), 16, 0, 0);
        }
        __syncthreads();

#pragma unroll
        for (int ks = 0; ks < 2; ++ks) {
            s16x8 af[4], bfr[4];
#pragma unroll
            for (int mt = 0; mt < 4; ++mt) {
                int row = wm * 64 + mt * 16 + lrow;
                af[mt] = *(const s16x8*)((const char*)As + row * 128 +
                                         ((ks * 64 + quad * 16) ^ swzr));
            }
#pragma unroll
            for (int nt = 0; nt < 4; ++nt) {
                int col = wn * 64 + nt * 16 + lrow;
                bfr[nt] = *(const s16x8*)((const char*)Bs + col * 128 +
                                          ((ks * 64 + quad * 16) ^ swzr));
            }
#pragma unroll
            for (int mt = 0; mt < 4; ++mt)
#pragma unroll
                for (int nt = 0; nt < 4; ++nt)
                    acc[mt][nt] = __builtin_amdgcn_mfma_f32_16x16x32_bf16(
                        bfr[nt], af[mt], acc[mt][nt], 0, 0, 0);  // swapped: D[row][col]
        }
        __syncthreads();
    }

    // epilogue (swapped layout): row = lane&15, cols = quad*4 + 0..3
    float4 bvv[4], wvv[4];
    if (KIND == 1 || KIND == 3 || KIND == 4) {
#pragma unroll
        for (int nt = 0; nt < 4; ++nt) {
            int col = n0 + wn * 64 + nt * 16 + quad * 4;
            bvv[nt] = *(const float4*)(xf + col);
            wvv[nt] = *(const float4*)(w2f + col);
        }
    }
#pragma unroll
    for (int mt = 0; mt < 4; ++mt) {
        const int row = m0 + wm * 64 + mt * 16 + lrow;
        const size_t rbase = (size_t)row * H;
#pragma unroll
        for (int nt = 0; nt < 4; ++nt) {
            const int col = n0 + wn * 64 + nt * 16 + quad * 4;
            const size_t idx = rbase + col;
            f32x4 a = acc[mt][nt];
            short4 o;
            if (KIND == 0) {
                float4 xv = *(const float4*)(xf + idx);
                o.x = f2b(a[0] + xv.x);
                o.y = f2b(a[1] + xv.y);
                o.z = f2b(a[2] + xv.z);
                o.w = f2b(a[3] + xv.w);
                *(short4*)(out + idx) = o;
            } else if (KIND == 1) {
                float t0 = ftanh(a[0] + bvv[nt].x);
                float t1 = ftanh(a[1] + bvv[nt].y);
                float t2 = ftanh(a[2] + bvv[nt].z);
                float t3 = ftanh(a[3] + bvv[nt].w);
                o.x = f2b((1.0f - t0 * t0) * wvv[nt].x);
                o.y = f2b((1.0f - t1 * t1) * wvv[nt].y);
                o.z = f2b((1.0f - t2 * t2) * wvv[nt].z);
                o.w = f2b((1.0f - t3 * t3) * wvv[nt].w);
                *(short4*)(out + idx) = o;
            } else if (KIND == 2) {
                short4 zo = *(const short4*)(out + idx);
                float d0 = fminf(fmaxf(a[0], -clampv), clampv);
                float d1 = fminf(fmaxf(a[1], -clampv), clampv);
                float d2 = fminf(fmaxf(a[2], -clampv), clampv);
                float d3 = fminf(fmaxf(a[3], -clampv), clampv);
                o.x = f2b(b2f(zo.x) + d0);
                o.y = f2b(b2f(zo.y) + d1);
                o.z = f2b(b2f(zo.z) + d2);
                o.w = f2b(b2f(zo.w) + d3);
                *(short4*)(out + idx) = o;
            } else if (KIND == 3) {
                short4 u;                       // u0 = bf16(acc)
                u.x = f2b(a[0]); u.y = f2b(a[1]); u.z = f2b(a[2]); u.w = f2b(a[3]);
                *(short4*)(out + idx) = u;
                float t0 = ftanh(a[0] + bvv[nt].x);
                float t1 = ftanh(a[1] + bvv[nt].y);
                float t2 = ftanh(a[2] + bvv[nt].z);
                float t3 = ftanh(a[3] + bvv[nt].w);
                o.x = f2b((1.0f - t0 * t0) * wvv[nt].x);
                o.y = f2b((1.0f - t1 * t1) * wvv[nt].y);
                o.z = f2b((1.0f - t2 * t2) * wvv[nt].z);
                o.w = f2b((1.0f - t3 * t3) * wvv[nt].w);
                *(short4*)(out2 + idx) = o;     // gsum0 = gate0
            } else if (KIND == 4) {
                short4 u4 = *(const short4*)(u0r + idx);
                short4 p4 = *(const short4*)(pg + idx);
                float t0 = ftanh(b2f(u4.x) + a[0] + bvv[nt].x);
                float t1 = ftanh(b2f(u4.y) + a[1] + bvv[nt].y);
                float t2 = ftanh(b2f(u4.z) + a[2] + bvv[nt].z);
                float t3 = ftanh(b2f(u4.w) + a[3] + bvv[nt].w);
                o.x = f2b(b2f(p4.x) + (1.0f - t0 * t0) * wvv[nt].x);
                o.y = f2b(b2f(p4.y) + (1.0f - t1 * t1) * wvv[nt].y);
                o.z = f2b(b2f(p4.z) + (1.0f - t2 * t2) * wvv[nt].z);
                o.w = f2b(b2f(p4.w) + (1.0f - t3 * t3) * wvv[nt].w);
                *(short4*)(out2 + idx) = o;     // gsum_s = gsum_{s-1} + gate_s
            } else if (KIND == 5) {              // GT = bf16(DT*acc)
                o.x = f2b(DT * a[0]);
                o.y = f2b(DT * a[1]);
                o.z = f2b(DT * a[2]);
                o.w = f2b(DT * a[3]);
                *(short4*)(out + idx) = o;
            } else {                             // KIND 7: z-delta = bf16(acc)
                o.x = f2b(a[0]);
                o.y = f2b(a[1]);
                o.z = f2b(a[2]);
                o.w = f2b(a[3]);
                *(short4*)(out + idx) = o;
            }
        }
    }
}

// ---------------- kernels ----------------

// D1: prep (blocks 0..255) || x->bf16 convert (blocks 256..2047, grid-stride)
__global__ __launch_bounds__(256)
void prep_cvt_k(const float* __restrict__ S, const float* __restrict__ W1,
                const float* __restrict__ x,
                short* __restrict__ Wsym, short* __restrict__ WsymT,
                short* __restrict__ W1b, short* __restrict__ WflowT,
                short* __restrict__ Wfd, short* __restrict__ xb) {
    __shared__ __align__(16) char smem[25088];
    const int b = blockIdx.x, tid = threadIdx.x;
    if (b < 256) {
        prep_tile(smem, S, W1, Wsym, WsymT, W1b, WflowT, Wfd, b, tid);
    } else {
        const int N8 = MROWS * H / 8;              // 2097152
        for (int t = (b - 256) * 256 + tid; t < N8; t += 1792 * 256) {
            const float4* p = (const float4*)x + (size_t)t * 2;
            float4 f0 = p[0], f1 = p[1];
            s16x8 v;
            v[0] = f2b(f0.x); v[1] = f2b(f0.y); v[2] = f2b(f0.z); v[3] = f2b(f0.w);
            v[4] = f2b(f1.x); v[5] = f2b(f1.y); v[6] = f2b(f1.z); v[7] = f2b(f1.w);
            ((s16x8*)xb)[t] = v;
        }
    }
}

// D3: K3 (u0+gate0, blocks 0..1023, XCD-swizzled) || GT (blocks 1024..1087)
__global__ __launch_bounds__(256, 4)
void k3_gt_k(const short* __restrict__ xb, const short* __restrict__ Wu,
             short* __restrict__ u0,
             const float* __restrict__ b1, const float* __restrict__ w2,
             short* __restrict__ gsumA,
             const short* __restrict__ W1b, const short* __restrict__ WflowT,
             short* __restrict__ GT) {
    __shared__ __align__(16) char smem[32768];
    const int b = blockIdx.x, tid = threadIdx.x;
    if (b < 1024) {
        const int chunk = ((b & 7) << 7) | (b >> 3);   // bijective XCD swizzle
        gemm_core<3>(smem, xb, Wu, u0, b1, w2, nullptr, nullptr, gsumA,
                     nullptr, nullptr, (chunk >> 3) * BM, (chunk & 7) * BN, tid, 0.0f);
    } else {
        const int bb = b - 1024;                        // 0..63
        gemm_core<5>(smem, W1b, WflowT, GT, nullptr, nullptr, nullptr, nullptr,
                     nullptr, nullptr, nullptr, (bb >> 3) * BM, (bb & 7) * BN, tid, 0.0f);
    }
}

// standalone prep (fallback path)
__global__ __launch_bounds__(256)
void prep_k(const float* __restrict__ S, const float* __restrict__ W1,
            short* __restrict__ Wsym, short* __restrict__ WsymT,
            short* __restrict__ W1b, short* __restrict__ WflowT,
            short* __restrict__ Wfd) {
    __shared__ __align__(16) char smem[25088];
    prep_tile(smem, S, W1, Wsym, WsymT, W1b, WflowT, Wfd, blockIdx.x, threadIdx.x);
}

__global__ __launch_bounds__(256)
void cvt_x(const float* __restrict__ x, short* __restrict__ xb) {
    int t = blockIdx.x * 256 + threadIdx.x;
    const float4* p = (const float4*)x + (size_t)t * 2;
    float4 f0 = p[0], f1 = p[1];
    s16x8 v;
    v[0] = f2b(f0.x); v[1] = f2b(f0.y); v[2] = f2b(f0.z); v[3] = f2b(f0.w);
    v[4] = f2b(f1.x); v[5] = f2b(f1.y); v[6] = f2b(f1.z); v[7] = f2b(f1.w);
    ((s16x8*)xb)[t] = v;
}

template <int KIND, bool G2D>
__global__ __launch_bounds__(256, 4)
void gemm_k(const short* A, const short* Bw, short* out,
            const float* xf, const float* w2f,
            const short* u0r, const short* pg, short* out2,
            const short* A2, const short* B2, float clampv) {
    __shared__ __align__(16) char smem[32768];
    int m0, n0;
    if (G2D) {
        m0 = blockIdx.y * BM;
        n0 = blockIdx.x * BN;
    } else {
        const int lid   = blockIdx.x;
        const int chunk = ((lid & 7) << 7) | (lid >> 3);
        m0 = (chunk >> 3) * BM;
        n0 = (chunk & 7) * BN;
    }
    gemm_core<KIND>(smem, A, Bw, out, xf, w2f, u0r, pg, out2, A2, B2,
                    m0, n0, threadIdx.x, clampv);
}

// y = xmul*x + z (z bf16, x fp32); LayerNorm over H; out FP32 (d_out).
__global__ __launch_bounds__(256)
void ln_k(const short* __restrict__ z, const float* __restrict__ x,
          const float* __restrict__ gamma, const float* __restrict__ beta,
          float* __restrict__ out, float xmul) {
    const int row = blockIdx.x;
    const int tid = threadIdx.x;
    const size_t base = (size_t)row * H;
    short4 z4 = ((const short4*)(z + base))[tid];
    float4 x4 = ((const float4*)(x + base))[tid];
    float y0 = fmaf(xmul, x4.x, b2f(z4.x));
    float y1 = fmaf(xmul, x4.y, b2f(z4.y));
    float y2 = fmaf(xmul, x4.z, b2f(z4.z));
    float y3 = fmaf(xmul, x4.w, b2f(z4.w));
    float s = y0 + y1 + y2 + y3;
    float q = y0 * y0 + y1 * y1 + y2 * y2 + y3 * y3;
#pragma unroll
    for (int off = 32; off > 0; off >>= 1) {
        s += __shfl_down(s, off);
        q += __shfl_down(q, off);
    }
    __shared__ float ss[4], qs[4];
    if ((tid & 63) == 0) { ss[tid >> 6] = s; qs[tid >> 6] = q; }
    __syncthreads();
    s = ss[0] + ss[1] + ss[2] + ss[3];
    q = qs[0] + qs[1] + qs[2] + qs[3];
    const float mu  = s * (1.0f / H);
    const float var = q * (1.0f / H) - mu * mu;
    const float rs  = rsqrtf(var + LN_EPS);
    const int col = tid * 4;
    float4 o;
    o.x = (y0 - mu) * rs * gamma[col + 0] + beta[col + 0];
    o.y = (y1 - mu) * rs * gamma[col + 1] + beta[col + 1];
    o.z = (y2 - mu) * rs * gamma[col + 2] + beta[col + 2];
    o.w = (y3 - mu) * rs * gamma[col + 3] + beta[col + 3];
    ((float4*)(out + base))[tid] = o;
}

extern "C" void kernel_launch(void* const* d_in, const int* in_sizes, int n_in,
                              void* d_out, int out_size, void* d_ws, size_t ws_size,
                              hipStream_t stream) {
    int ix = 0;
    for (int i = 0; i < n_in; ++i)
        if (in_sizes[i] == MROWS * H) { ix = i; break; }

    const float *x, *S, *W1, *b1, *w2, *gamma, *beta;
    if (ix == 0) {
        // dict order: x,S,W1,b1,w2,b2,J,gamma,beta,num_steps
        x     = (const float*)d_in[0];
        S     = (const float*)d_in[1];
        W1    = (const float*)d_in[2];
        b1    = (const float*)d_in[3];
        w2    = (const float*)d_in[4];
        gamma = (const float*)d_in[7];
        beta  = (const float*)d_in[8];
    } else {
        // sorted-key order: J,S,W1,b1,b2,beta,gamma,num_steps,w2,x
        S     = (const float*)d_in[1];
        W1    = (const float*)d_in[2];
        b1    = (const float*)d_in[3];
        beta  = (const float*)d_in[5];
        gamma = (const float*)d_in[6];
        w2    = (const float*)d_in[8];
        x     = (const float*)d_in[ix];
    }

    const size_t MB = 1024 * 1024;
    // d_out (64MB):
    //   [0..32):  u0 (bf16, written by K3, dead after last K4)
    //   [32..46): Wsym | WsymT | W1b | WflowT | Wfd | Wu | GT   (2MB each)
    //   final LN overwrites all 64MB with fp32 out.
    float* out    = (float*)d_out;
    short* u0     = (short*)d_out;
    char*  hi     = (char*)d_out + 32 * MB;
    short* Wsym   = (short*)(hi);
    short* WsymT  = (short*)(hi + 2 * MB);
    short* W1b    = (short*)(hi + 4 * MB);
    short* WflowT = (short*)(hi + 6 * MB);
    short* Wfd    = (short*)(hi + 8 * MB);
    short* Wu     = (short*)(hi + 10 * MB);
    short* GT     = (short*)(hi + 12 * MB);
    // d_ws (fast, >=96MB): [0..32) xb | [32..64) gsumA | [64..96) gsumB -> z
    short* xb     = (short*)d_ws;
    short* gsumA  = (short*)((char*)d_ws + 32 * MB);
    short* gsumB  = (short*)((char*)d_ws + 64 * MB);
    short* z      = gsumB;

    const bool fast = ws_size >= 96 * MB;
    const int  nblk = (H / BN) * (MROWS / BM);  // 1024

    if (fast) {
        // D1: prep || cvt
        prep_cvt_k<<<2048, 256, 0, stream>>>(S, W1, x, Wsym, WsymT, W1b,
                                             WflowT, Wfd, xb);
        // D2: Wu = W1 + W1b@WsymT^T
        gemm_k<0, true><<<dim3(H / BN, H / BM), 256, 0, stream>>>(
            W1b, WsymT, Wu, W1, nullptr, nullptr, nullptr, nullptr,
            nullptr, nullptr, 0.0f);
        // D3: u0 = x@Wu^T, gsumA = gate0  ||  GT = DT*(W1b@WflowT^T)
        k3_gt_k<<<1088, 256, 0, stream>>>(xb, Wu, u0, b1, w2, gsumA,
                                          W1b, WflowT, GT);
        // D4: gsumB = gsumA + gate1
        gemm_k<4, false><<<nblk, 256, 0, stream>>>(
            gsumA, GT, nullptr, b1, w2, u0, gsumA, gsumB,
            nullptr, nullptr, 0.0f);
        // D5: gsumA = gsumB + gate2
        gemm_k<4, false><<<nblk, 256, 0, stream>>>(
            gsumB, GT, nullptr, b1, w2, u0, gsumB, gsumA,
            nullptr, nullptr, 0.0f);
        // D6: z = x@Wsym^T + gsumA@Wfd^T   (K=2048 fused; y = 2x + z)
        gemm_k<7, false><<<nblk, 256, 0, stream>>>(
            xb, Wsym, z, nullptr, nullptr, nullptr, nullptr, nullptr,
            gsumA, Wfd, 0.0f);
        // D7: LayerNorm
        ln_k<<<MROWS, 256, 0, stream>>>(z, x, gamma, beta, out, 2.0f);
    } else {
        // fallback (ws >= 32MB): proven 7-GEMM sequence; y = x + z
        short* xbo = (short*)d_out;          // xb in d_out, dead after KIND0
        short* go  = (short*)d_out;          // then reused as g
        short* zf  = (short*)d_ws;
        prep_k<<<256, 256, 0, stream>>>(S, W1, Wsym, WsymT, W1b, WflowT, Wfd);
        cvt_x<<<(MROWS * H / 8) / 256, 256, 0, stream>>>(x, xbo);
        gemm_k<0, false><<<nblk, 256, 0, stream>>>(
            xbo, Wsym, zf, x, nullptr, nullptr, nullptr, nullptr,
            nullptr, nullptr, 0.0f);
        for (int step = 0; step < 3; ++step) {
            gemm_k<1, false><<<nblk, 256, 0, stream>>>(
                zf, W1b, go, b1, w2, nullptr, nullptr, nullptr,
                nullptr, nullptr, 0.0f);
            gemm_k<2, false><<<nblk, 256, 0, stream>>>(
                go, Wfd, zf, nullptr, nullptr, nullptr, nullptr, nullptr,
                nullptr, nullptr, 0.01f);
        }
        ln_k<<<MROWS, 256, 0, stream>>>(zf, x, gamma, beta, out, 1.0f);
    }
}